// Round 7
// baseline (568.038 us; speedup 1.0000x reference)
//
#include <hip/hip_runtime.h>

#define L_NODES 16384
#define E_EDGES 131072
#define CDIM 512
#define QKVDIM 1536
#define HEADS 8
#define DHEAD 64
#define HID 1024

typedef __attribute__((ext_vector_type(8))) short bf16x8;
typedef __attribute__((ext_vector_type(4))) float f32x4;

__device__ inline unsigned short f2b(float f) {
    union { float f; unsigned int u; } v{f};
    unsigned int r = (v.u + 0x7fffu + ((v.u >> 16) & 1u)) >> 16;
    return (unsigned short)r;
}
__device__ inline float b2f(unsigned short h) {
    union { unsigned int u; float f; } v;
    v.u = (unsigned int)h << 16;
    return v.f;
}

// ---------------- LayerNorm (fp32 in -> bf16 out) ----------------
__global__ __launch_bounds__(256) void ln_bf16_kernel(
    const float* __restrict__ x, const float* __restrict__ g,
    const float* __restrict__ b, short* __restrict__ out)
{
    int row = blockIdx.x;
    int t = threadIdx.x;
    const float2* xr = (const float2*)(x + (size_t)row * CDIM);
    float2 v = xr[t];
    float s = v.x + v.y;
    float sq = v.x * v.x + v.y * v.y;
    for (int off = 32; off; off >>= 1) {
        s += __shfl_xor(s, off);
        sq += __shfl_xor(sq, off);
    }
    __shared__ float ss[4], sqs[4];
    int wave = t >> 6, lane = t & 63;
    if (lane == 0) { ss[wave] = s; sqs[wave] = sq; }
    __syncthreads();
    s = ss[0] + ss[1] + ss[2] + ss[3];
    sq = sqs[0] + sqs[1] + sqs[2] + sqs[3];
    float mu = s * (1.0f / CDIM);
    float var = sq * (1.0f / CDIM) - mu * mu;
    float inv = rsqrtf(var + 1e-5f);
    int c = t * 2;
    unsigned short h0 = f2b((v.x - mu) * inv * g[c] + b[c]);
    unsigned short h1 = f2b((v.y - mu) * inv * g[c + 1] + b[c + 1]);
    unsigned int packed = ((unsigned int)h1 << 16) | h0;
    *(unsigned int*)(out + (size_t)row * CDIM + c) = packed;
}

// ---------------- Prep: all weight transposes + bias pack + cnt zero, one launch ----
__global__ __launch_bounds__(256) void prep_kernel(
    const float* __restrict__ Wq, const float* __restrict__ Wk,
    const float* __restrict__ Wv, const float* __restrict__ Wo,
    const float* __restrict__ W1, const float* __restrict__ W2,
    short* __restrict__ wqkvT, short* __restrict__ woT,
    short* __restrict__ w1T, short* __restrict__ w2T,
    const float* __restrict__ bq, const float* __restrict__ bk,
    const float* __restrict__ bv, float* __restrict__ bqkv,
    int* __restrict__ cnt)
{
    int bid = blockIdx.x;
    if (bid >= 2054) {                       // zero cnt
        cnt[(bid - 2054) * 256 + threadIdx.x] = 0;
        return;
    }
    if (bid >= 2048) {                       // bias pack (1536 elems over 6 blocks)
        int i = (bid - 2048) * 256 + threadIdx.x;
        float val = (i < CDIM) ? bq[i] : (i < 2 * CDIM) ? bk[i - CDIM] : bv[i - 2 * CDIM];
        bqkv[i] = val;
        return;
    }
    const float* W; short* WT; int K, N, tn, tk;
    if (bid < 1024) {
        int w = bid >> 8, local = bid & 255;
        tn = local & 15; tk = local >> 4; K = 512; N = 512;
        W = (w == 0) ? Wq : (w == 1) ? Wk : (w == 2) ? Wv : Wo;
        WT = (w == 3) ? woT : wqkvT + (size_t)w * 512 * 512;
    } else if (bid < 1536) {
        int local = bid - 1024;
        tn = local & 31; tk = local >> 5; K = 512; N = 1024;
        W = W1; WT = w1T;
    } else {
        int local = bid - 1536;
        tn = local & 15; tk = local >> 4; K = 1024; N = 512;
        W = W2; WT = w2T;
    }
    __shared__ float tile[32][33];
    int tx = threadIdx.x & 31, ty = threadIdx.x >> 5;
    int n0 = tn * 32, k0 = tk * 32;
#pragma unroll
    for (int r = 0; r < 4; r++)
        tile[ty + r * 8][tx] = W[(size_t)(k0 + ty + r * 8) * N + n0 + tx];
    __syncthreads();
#pragma unroll
    for (int r = 0; r < 4; r++)
        WT[(size_t)(n0 + ty + r * 8) * K + k0 + tx] = f2b(tile[tx][ty + r * 8]);
}

// ---------------- bf16 MFMA GEMM, no-LDS register-direct ----------------
// C[M][N] = A[M][K] @ B^T[N][K]. Block = 256 thr = 4 waves; each wave owns a
// (BM/2)x64 output tile and loads its MFMA fragments straight from global
// (global_load_dwordx4; one 64B line per A-row per 32-k window). No LDS, no
// barriers -> no compiler-forced vmcnt(0) drain; distance-1 register prefetch
// + 3-4 free-running waves/SIMD hide L2/L3 latency.
template<int BM>
__global__ __launch_bounds__(256) void gemm_bf16_kernel(
    const short* __restrict__ A, const short* __restrict__ B,
    const float* __restrict__ bias, const float* __restrict__ res,
    float* __restrict__ outf, short* __restrict__ outb,
    int M, int N, int K, int act)
{
    constexpr int MI = BM / 32;              // 16-row tiles per wave (4 or 2)
    int t = threadIdx.x;
    int bm = blockIdx.y * BM, bn = blockIdx.x * 128;
    int wave = t >> 6, lane = t & 63;
    int wm = (wave & 1) * (BM / 2), wn = (wave >> 1) * 64;
    int crow = lane & 15, quad = lane >> 4;

    f32x4 acc[MI][4] = {};

    const short* Ap[MI];
    const short* Bp[4];
#pragma unroll
    for (int i = 0; i < MI; i++)
        Ap[i] = A + (size_t)(bm + wm + i * 16 + crow) * K + quad * 8;
#pragma unroll
    for (int j = 0; j < 4; j++)
        Bp[j] = B + (size_t)(bn + wn + j * 16 + crow) * K + quad * 8;

    bf16x8 a_n[MI], b_n[4];
#pragma unroll
    for (int i = 0; i < MI; i++) a_n[i] = *(const bf16x8*)Ap[i];
#pragma unroll
    for (int j = 0; j < 4; j++)  b_n[j] = *(const bf16x8*)Bp[j];

    const int niter = K >> 5;
    for (int it = 0; it < niter; ++it) {
        bf16x8 a_c[MI], b_c[4];
#pragma unroll
        for (int i = 0; i < MI; i++) a_c[i] = a_n[i];
#pragma unroll
        for (int j = 0; j < 4; j++)  b_c[j] = b_n[j];
        if (it + 1 < niter) {
            int off = (it + 1) << 5;
#pragma unroll
            for (int i = 0; i < MI; i++) a_n[i] = *(const bf16x8*)(Ap[i] + off);
#pragma unroll
            for (int j = 0; j < 4; j++)  b_n[j] = *(const bf16x8*)(Bp[j] + off);
        }
#pragma unroll
        for (int i = 0; i < MI; i++)
#pragma unroll
            for (int j = 0; j < 4; j++)
                acc[i][j] = __builtin_amdgcn_mfma_f32_16x16x32_bf16(a_c[i], b_c[j], acc[i][j], 0, 0, 0);
    }

#pragma unroll
    for (int i = 0; i < MI; i++) {
#pragma unroll
        for (int j = 0; j < 4; j++) {
            int n = bn + wn + j * 16 + crow;
            float bi = bias ? bias[n] : 0.0f;
#pragma unroll
            for (int r = 0; r < 4; r++) {
                int mrow = bm + wm + i * 16 + quad * 4 + r;
                float val = acc[i][j][r] + bi;
                if (act) {
                    // gelu(tanh approx) == val * sigmoid(2*0.79788456*(val+0.044715*val^3))
                    float u = 1.5957691216057308f * (val + 0.044715f * val * val * val);
                    val = val / (1.0f + __expf(-u));
                }
                if (res) val += res[(size_t)mrow * N + n];
                if (outf) outf[(size_t)mrow * N + n] = val;
                if (outb) outb[(size_t)mrow * N + n] = f2b(val);
            }
        }
    }
}

// ---------------- CSR build ----------------
__global__ void hist_kernel(const int* __restrict__ row_index, int* __restrict__ cnt)
{
    int e = blockIdx.x * 256 + threadIdx.x;
    if (e < E_EDGES) atomicAdd(&cnt[row_index[e]], 1);
}

__global__ void scan_kernel(const int* __restrict__ cnt, int* __restrict__ row_start,
                            int* __restrict__ cursor)
{
    int t = threadIdx.x; // 64 threads, 1 wave
    const int PER = L_NODES / 64; // 256
    int local = 0;
    for (int i = 0; i < PER; i++) local += cnt[t * PER + i];
    int v = local;
    for (int off = 1; off < 64; off <<= 1) {
        int u = __shfl_up(v, off);
        if (t >= off) v += u;
    }
    int run = v - local; // exclusive prefix
    for (int i = 0; i < PER; i++) {
        row_start[t * PER + i] = run;
        cursor[t * PER + i] = run;
        run += cnt[t * PER + i];
    }
    if (t == 63) row_start[L_NODES] = run;
}

// scatter: emeta[p] = (col, r0, r1, r2); pabp[p*8+h] = pos_att_bias[e*8+h]
__global__ void scatter_kernel(const int* __restrict__ row_index, const int* __restrict__ col_index,
                               const int* __restrict__ to_col_index, const float* __restrict__ dist,
                               const float* __restrict__ pos, const float* __restrict__ col_pos,
                               const float* __restrict__ pos_att_bias,
                               int* __restrict__ cursor, int4* __restrict__ emeta,
                               float* __restrict__ pabp)
{
    int e = blockIdx.x * 256 + threadIdx.x;
    if (e < E_EDGES) {
        int row = row_index[e];
        int p = atomicAdd(&cursor[row], 1);
        int tci = to_col_index[e];
        float dinv = 1.0f / dist[e];
        float r0 = (col_pos[tci * 3]     - pos[row * 3])     * dinv;
        float r1 = (col_pos[tci * 3 + 1] - pos[row * 3 + 1]) * dinv;
        float r2 = (col_pos[tci * 3 + 2] - pos[row * 3 + 2]) * dinv;
        emeta[p] = make_int4(col_index[e], __float_as_int(r0), __float_as_int(r1),
                             __float_as_int(r2));
        const float4* pb = (const float4*)(pos_att_bias + (size_t)e * HEADS);
        float4 b0 = pb[0], b1 = pb[1];
        float4* dst = (float4*)(pabp + (size_t)p * HEADS);
        dst[0] = b0; dst[1] = b1;
    }
}

// ---------------- Edge attention: wave = row (all heads), serial edge loop -----------
__global__ __launch_bounds__(256) void attn_kernel(
    const short* __restrict__ qkv, const int4* __restrict__ emeta,
    const float* __restrict__ pabp, const int* __restrict__ row_start,
    const float* __restrict__ Wvec, const float* __restrict__ bvec,
    short* __restrict__ out_bf)
{
    int lane = threadIdx.x & 63;
    int r = blockIdx.x * 4 + (threadIdx.x >> 6);
    int h = lane >> 3;
    int cbase = lane * 8;                // channels [cbase, cbase+8) of C=512

    float qv[8], wv0[8], wv1[8], wv2[8], bvv[8];
    {
        bf16x8 qh = *(const bf16x8*)(qkv + (size_t)r * QKVDIM + cbase);
#pragma unroll
        for (int j = 0; j < 8; j++) qv[j] = b2f((unsigned short)qh[j]);
        float4 a0 = *(const float4*)(Wvec + cbase);
        float4 a1 = *(const float4*)(Wvec + cbase + 4);
        float4 b0 = *(const float4*)(Wvec + CDIM + cbase);
        float4 b1 = *(const float4*)(Wvec + CDIM + cbase + 4);
        float4 c0 = *(const float4*)(Wvec + 2 * CDIM + cbase);
        float4 c1 = *(const float4*)(Wvec + 2 * CDIM + cbase + 4);
        float4 d0 = *(const float4*)(bvec + cbase);
        float4 d1 = *(const float4*)(bvec + cbase + 4);
        wv0[0]=a0.x; wv0[1]=a0.y; wv0[2]=a0.z; wv0[3]=a0.w; wv0[4]=a1.x; wv0[5]=a1.y; wv0[6]=a1.z; wv0[7]=a1.w;
        wv1[0]=b0.x; wv1[1]=b0.y; wv1[2]=b0.z; wv1[3]=b0.w; wv1[4]=b1.x; wv1[5]=b1.y; wv1[6]=b1.z; wv1[7]=b1.w;
        wv2[0]=c0.x; wv2[1]=c0.y; wv2[2]=c0.z; wv2[3]=c0.w; wv2[4]=c1.x; wv2[5]=c1.y; wv2[6]=c1.z; wv2[7]=c1.w;
        bvv[0]=d0.x; bvv[1]=d0.y; bvv[2]=d0.z; bvv[3]=d0.w; bvv[4]=d1.x; bvv[5]=d1.y; bvv[6]=d1.z; bvv[7]=d1.w;
    }

    int e0 = row_start[r], e1 = row_start[r + 1];
    float m = -1e30f, l = 0.0f;
    float acc[8] = {};

    // 2-deep software pipeline: emeta fetched 2 ahead, k/v + bias fetched 1 ahead.
    int4 em_n, em_n2;
    float pab_n;
    bf16x8 k_n, v_n;
    if (e0 < e1) {
        em_n = emeta[e0];
        em_n2 = emeta[(e0 + 1 < e1) ? e0 + 1 : e1 - 1];
        pab_n = pabp[(size_t)e0 * HEADS + h];
        const short* kp = qkv + (size_t)em_n.x * QKVDIM + CDIM + cbase;
        k_n = *(const bf16x8*)kp;
        v_n = *(const bf16x8*)(kp + CDIM);
    }
    for (int idx = e0; idx < e1; ++idx) {
        int4 em = em_n;
        float pab = pab_n;
        bf16x8 k8 = k_n, v8 = v_n;
        // advance pipeline
        em_n = em_n2;
        int i2 = (idx + 2 < e1) ? idx + 2 : e1 - 1;
        em_n2 = emeta[i2];
        int i1 = (idx + 1 < e1) ? idx + 1 : e1 - 1;
        pab_n = pabp[(size_t)i1 * HEADS + h];
        {
            const short* kp = qkv + (size_t)em_n.x * QKVDIM + CDIM + cbase;
            k_n = *(const bf16x8*)kp;
            v_n = *(const bf16x8*)(kp + CDIM);
        }
        // compute current edge
        float s = 0.0f;
        float vf[8];
#pragma unroll
        for (int j = 0; j < 8; j++) {
            float kf = b2f((unsigned short)k8[j]);
            vf[j] = b2f((unsigned short)v8[j]);
            float d = qv[j] - kf;
            s = fmaf(d, d, s);
        }
        s += __shfl_xor(s, 1);
        s += __shfl_xor(s, 2);
        s += __shfl_xor(s, 4);              // per-head dot (8 lanes of head h)
        float score = -s * 0.125f + pab;
        float mn = fmaxf(m, score);
        float scale = __expf(m - mn);
        float pexp = __expf(score - mn);
        m = mn;
        l = l * scale + pexp;
        float r0 = __int_as_float(em.y), r1 = __int_as_float(em.z), r2 = __int_as_float(em.w);
#pragma unroll
        for (int j = 0; j < 8; j++) {
            float vv = vf[j] + r0 * wv0[j] + r1 * wv1[j] + r2 * wv2[j] + bvv[j];
            acc[j] = fmaf(acc[j], scale, pexp * vv);
        }
    }
    float inv = (l > 0.0f) ? 1.0f / l : 0.0f;
    bf16x8 o;
#pragma unroll
    for (int j = 0; j < 8; j++) o[j] = (short)f2b(acc[j] * inv);
    *(bf16x8*)(out_bf + (size_t)r * CDIM + cbase) = o;
}

// ---------------- launch ----------------
extern "C" void kernel_launch(void* const* d_in, const int* in_sizes, int n_in,
                              void* d_out, int out_size, void* d_ws, size_t ws_size,
                              hipStream_t stream)
{
    const float* x            = (const float*)d_in[0];
    const int*   row_index    = (const int*)d_in[1];
    const int*   col_index    = (const int*)d_in[2];
    const int*   to_col_index = (const int*)d_in[3];
    const float* pos_att_bias = (const float*)d_in[5];
    const float* dist         = (const float*)d_in[6];
    const float* pos          = (const float*)d_in[7];
    const float* col_pos      = (const float*)d_in[8];
    const float* ln1_g = (const float*)d_in[9];
    const float* ln1_b = (const float*)d_in[10];
    const float* ln2_g = (const float*)d_in[11];
    const float* ln2_b = (const float*)d_in[12];
    const float* Wq = (const float*)d_in[13];  const float* bq = (const float*)d_in[14];
    const float* Wk = (const float*)d_in[15];  const float* bk = (const float*)d_in[16];
    const float* Wv = (const float*)d_in[17];  const float* bv = (const float*)d_in[18];
    const float* Wvec = (const float*)d_in[19]; const float* bvec = (const float*)d_in[20];
    const float* Wo = (const float*)d_in[21];  const float* bo = (const float*)d_in[22];
    const float* W1 = (const float*)d_in[23];  const float* b1 = (const float*)d_in[24];
    const float* W2 = (const float*)d_in[25];  const float* b2 = (const float*)d_in[26];

    char* ws = (char*)d_ws;
    size_t off = 0;
    auto alloc = [&](size_t bytes) -> void* {
        void* p = ws + off;
        off = (off + bytes + 255) & ~(size_t)255;
        return p;
    };
    const size_t LC = (size_t)L_NODES * CDIM;
    short* qkvb = (short*)alloc((size_t)L_NODES * QKVDIM * 2);  // q|k|v bf16
    float* x1f  = (float*)alloc(LC * 4);
    short* zbf  = (short*)alloc(LC * 2);            // LN1 out, reused for LN2 out
    short* abf  = (short*)alloc(LC * 2);            // attention out (bf16)
    short* wqkvT = (short*)alloc((size_t)QKVDIM * CDIM * 2);
    short* woT   = (short*)alloc((size_t)CDIM * CDIM * 2);
    short* w1T   = (short*)alloc((size_t)CDIM * HID * 2);
    short* w2T   = (short*)alloc((size_t)HID * CDIM * 2);
    float* bqkv  = (float*)alloc(QKVDIM * 4);
    int* cnt       = (int*)alloc(L_NODES * 4);
    int* cursor    = (int*)alloc(L_NODES * 4);
    int* row_start = (int*)alloc((L_NODES + 1) * 4);
    int4* emeta    = (int4*)alloc((size_t)E_EDGES * 16);
    short* hbf = (short*)qkvb;   // hidden bf16 (L x HID) overlays qkvb (dead after attention)
    float* pabp = x1f;           // permuted bias overlays x1f (x1f written only after attn)

    // prep: all transposes + bias pack + cnt zero (1 launch)
    prep_kernel<<<2118, 256, 0, stream>>>(Wq, Wk, Wv, Wo, W1, W2,
                                          wqkvT, woT, w1T, w2T,
                                          bq, bk, bv, bqkv, cnt);

    // LN1
    ln_bf16_kernel<<<L_NODES, 256, 0, stream>>>(x, ln1_g, ln1_b, zbf);

    // fused QKV GEMM: [16384,1536] bf16
    dim3 gqkv(QKVDIM / 128, L_NODES / 128);
    gemm_bf16_kernel<128><<<gqkv, 256, 0, stream>>>(zbf, wqkvT, bqkv, nullptr, nullptr, qkvb,
                                                    L_NODES, QKVDIM, CDIM, 0);

    // CSR build
    hist_kernel<<<E_EDGES / 256, 256, 0, stream>>>(row_index, cnt);
    scan_kernel<<<1, 64, 0, stream>>>(cnt, row_start, cursor);
    scatter_kernel<<<E_EDGES / 256, 256, 0, stream>>>(row_index, col_index, to_col_index,
                                                      dist, pos, col_pos, pos_att_bias,
                                                      cursor, emeta, pabp);

    // edge attention: wave per row, 4 rows per 256-thread block
    attn_kernel<<<L_NODES / 4, 256, 0, stream>>>(qkvb, emeta, pabp, row_start, Wvec, bvec, abf);

    // Wo GEMM + residual -> x1  (BM=64: 1024 blocks for TLP)
    dim3 gwo(CDIM / 128, L_NODES / 64);
    gemm_bf16_kernel<64><<<gwo, 256, 0, stream>>>(abf, woT, bo, x, x1f, nullptr, L_NODES, CDIM, CDIM, 0);

    // LN2
    ln_bf16_kernel<<<L_NODES, 256, 0, stream>>>(x1f, ln2_g, ln2_b, zbf);

    // FFN
    dim3 g1024(HID / 128, L_NODES / 128);
    gemm_bf16_kernel<128><<<g1024, 256, 0, stream>>>(zbf, w1T, b1, nullptr, nullptr, hbf, L_NODES, HID, CDIM, 1);
    dim3 gw2(CDIM / 128, L_NODES / 64);
    gemm_bf16_kernel<64><<<gw2, 256, 0, stream>>>(hbf, w2T, b2, x1f, (float*)d_out, nullptr, L_NODES, CDIM, HID, 0);
}

// Round 8
// 467.101 us; speedup vs baseline: 1.2161x; 1.2161x over previous
//
#include <hip/hip_runtime.h>

#define L_NODES 16384
#define E_EDGES 131072
#define CDIM 512
#define QKVDIM 1536
#define HEADS 8
#define DHEAD 64
#define HID 1024

typedef __attribute__((ext_vector_type(8))) short bf16x8;
typedef __attribute__((ext_vector_type(4))) float f32x4;

__device__ inline unsigned short f2b(float f) {
    union { float f; unsigned int u; } v{f};
    unsigned int r = (v.u + 0x7fffu + ((v.u >> 16) & 1u)) >> 16;
    return (unsigned short)r;
}
__device__ inline float b2f(unsigned short h) {
    union { unsigned int u; float f; } v;
    v.u = (unsigned int)h << 16;
    return v.f;
}

// async global->LDS, 16B per lane (wave-uniform base + lane*16 semantics)
__device__ inline void async_lds16(const void* g, void* l) {
    __builtin_amdgcn_global_load_lds(
        (const __attribute__((address_space(1))) unsigned int*)g,
        (__attribute__((address_space(3))) unsigned int*)l,
        16, 0, 0);
}

// ---------------- LayerNorm (fp32 in -> bf16 out) ----------------
__global__ __launch_bounds__(256) void ln_bf16_kernel(
    const float* __restrict__ x, const float* __restrict__ g,
    const float* __restrict__ b, short* __restrict__ out)
{
    int row = blockIdx.x;
    int t = threadIdx.x;
    const float2* xr = (const float2*)(x + (size_t)row * CDIM);
    float2 v = xr[t];
    float s = v.x + v.y;
    float sq = v.x * v.x + v.y * v.y;
    for (int off = 32; off; off >>= 1) {
        s += __shfl_xor(s, off);
        sq += __shfl_xor(sq, off);
    }
    __shared__ float ss[4], sqs[4];
    int wave = t >> 6, lane = t & 63;
    if (lane == 0) { ss[wave] = s; sqs[wave] = sq; }
    __syncthreads();
    s = ss[0] + ss[1] + ss[2] + ss[3];
    sq = sqs[0] + sqs[1] + sqs[2] + sqs[3];
    float mu = s * (1.0f / CDIM);
    float var = sq * (1.0f / CDIM) - mu * mu;
    float inv = rsqrtf(var + 1e-5f);
    int c = t * 2;
    unsigned short h0 = f2b((v.x - mu) * inv * g[c] + b[c]);
    unsigned short h1 = f2b((v.y - mu) * inv * g[c + 1] + b[c + 1]);
    unsigned int packed = ((unsigned int)h1 << 16) | h0;
    *(unsigned int*)(out + (size_t)row * CDIM + c) = packed;
}

// ---------------- Prep: all weight transposes + bias pack + cnt zero, one launch ----
__global__ __launch_bounds__(256) void prep_kernel(
    const float* __restrict__ Wq, const float* __restrict__ Wk,
    const float* __restrict__ Wv, const float* __restrict__ Wo,
    const float* __restrict__ W1, const float* __restrict__ W2,
    short* __restrict__ wqkvT, short* __restrict__ woT,
    short* __restrict__ w1T, short* __restrict__ w2T,
    const float* __restrict__ bq, const float* __restrict__ bk,
    const float* __restrict__ bv, float* __restrict__ bqkv,
    int* __restrict__ cnt)
{
    int bid = blockIdx.x;
    if (bid >= 2054) {                       // zero cnt
        cnt[(bid - 2054) * 256 + threadIdx.x] = 0;
        return;
    }
    if (bid >= 2048) {                       // bias pack (1536 elems over 6 blocks)
        int i = (bid - 2048) * 256 + threadIdx.x;
        float val = (i < CDIM) ? bq[i] : (i < 2 * CDIM) ? bk[i - CDIM] : bv[i - 2 * CDIM];
        bqkv[i] = val;
        return;
    }
    const float* W; short* WT; int K, N, tn, tk;
    if (bid < 1024) {
        int w = bid >> 8, local = bid & 255;
        tn = local & 15; tk = local >> 4; K = 512; N = 512;
        W = (w == 0) ? Wq : (w == 1) ? Wk : (w == 2) ? Wv : Wo;
        WT = (w == 3) ? woT : wqkvT + (size_t)w * 512 * 512;
    } else if (bid < 1536) {
        int local = bid - 1024;
        tn = local & 31; tk = local >> 5; K = 512; N = 1024;
        W = W1; WT = w1T;
    } else {
        int local = bid - 1536;
        tn = local & 15; tk = local >> 4; K = 1024; N = 512;
        W = W2; WT = w2T;
    }
    __shared__ float tile[32][33];
    int tx = threadIdx.x & 31, ty = threadIdx.x >> 5;
    int n0 = tn * 32, k0 = tk * 32;
#pragma unroll
    for (int r = 0; r < 4; r++)
        tile[ty + r * 8][tx] = W[(size_t)(k0 + ty + r * 8) * N + n0 + tx];
    __syncthreads();
#pragma unroll
    for (int r = 0; r < 4; r++)
        WT[(size_t)(n0 + ty + r * 8) * K + k0 + tx] = f2b(tile[tx][ty + r * 8]);
}

// ---------------- bf16 MFMA GEMM, 3-stage pipelined LDS K-loop ----------------
// C[M][N] = A[M][K] @ B^T[N][K]. BM x 128 tile, BK=32, 3 LDS stages.
// BM=256: 32 MFMA per wave per barrier (2x the drain amortization of BM=128).
template<int BM>
__global__ __launch_bounds__(256) void gemm_bf16_kernel(
    const short* __restrict__ A, const short* __restrict__ B,
    const float* __restrict__ bias, const float* __restrict__ res,
    float* __restrict__ outf, short* __restrict__ outb,
    int M, int N, int K, int act)
{
    constexpr int MI = BM / 32;              // 16-row tiles per wave (8/4/2)
    constexpr int LPI_A = BM / 64;           // A staging loads per thread per stage
    constexpr int STAGE_A = BM * 64;         // bytes per A stage
    constexpr int STAGE_B = 8192;            // bytes per B stage
    __shared__ short As[3 * BM * 32];
    __shared__ short Bs[3 * 128 * 32];
    int t = threadIdx.x;
    int bm = blockIdx.y * BM, bn = blockIdx.x * 128;
    int wave = t >> 6, lane = t & 63;
    int wm = (wave & 1) * (BM / 2), wn = (wave >> 1) * 64;
    int crow = lane & 15, quad = lane >> 4;

    f32x4 acc[MI][4] = {};

    const int niter = K >> 5;
    auto stage = [&](int s, int k0) {
#pragma unroll
        for (int a = 0; a < LPI_A; a++) {
            int idx = a * 256 + t;
            int row = idx >> 2, chunk = idx & 3;
            async_lds16(A + (size_t)(bm + row) * K + k0 + chunk * 8,
                        (char*)As + s * STAGE_A + idx * 16);
        }
#pragma unroll
        for (int c = 0; c < 2; c++) {
            int idx = c * 256 + t;
            int row = idx >> 2, chunk = idx & 3;
            async_lds16(B + (size_t)(bn + row) * K + k0 + chunk * 8,
                        (char*)Bs + s * STAGE_B + idx * 16);
        }
    };

    stage(0, 0);
    stage(1, 32);                            // K >= 64 always here

    for (int i = 0; i < niter; ++i) {
        int cur = i % 3;
        if (i + 1 < niter) {
            // drain only iter-i's stage (oldest in FIFO); keep i+1's in flight
            if constexpr (BM == 256)      asm volatile("s_waitcnt vmcnt(6)" ::: "memory");
            else if constexpr (BM == 128) asm volatile("s_waitcnt vmcnt(4)" ::: "memory");
            else                          asm volatile("s_waitcnt vmcnt(3)" ::: "memory");
        } else {
            asm volatile("s_waitcnt vmcnt(0)" ::: "memory");
        }
        __builtin_amdgcn_s_barrier();
        if (i + 2 < niter) stage((i + 2) % 3, (i + 2) << 5);

        const short* Ab = As + cur * (BM * 32);
        const short* Bb = Bs + cur * (128 * 32);
        bf16x8 af[MI], bg[4];
#pragma unroll
        for (int ii = 0; ii < MI; ii++)
            af[ii] = *(const bf16x8*)&Ab[(wm + ii * 16 + crow) * 32 + quad * 8];
#pragma unroll
        for (int j = 0; j < 4; j++)
            bg[j] = *(const bf16x8*)&Bb[(wn + j * 16 + crow) * 32 + quad * 8];
#pragma unroll
        for (int ii = 0; ii < MI; ii++)
#pragma unroll
            for (int j = 0; j < 4; j++)
                acc[ii][j] = __builtin_amdgcn_mfma_f32_16x16x32_bf16(af[ii], bg[j], acc[ii][j], 0, 0, 0);
        // no trailing barrier: each wave's ds_reads complete (lgkmcnt) before its
        // MFMAs, hence before it reaches the next iteration's barrier.
    }

#pragma unroll
    for (int i = 0; i < MI; i++) {
#pragma unroll
        for (int j = 0; j < 4; j++) {
            int n = bn + wn + j * 16 + crow;
            float bi = bias ? bias[n] : 0.0f;
#pragma unroll
            for (int r = 0; r < 4; r++) {
                int mrow = bm + wm + i * 16 + quad * 4 + r;
                float val = acc[i][j][r] + bi;
                if (act) {
                    // gelu(tanh approx) == val * sigmoid(2*0.79788456*(val+0.044715*val^3))
                    float u = 1.5957691216057308f * (val + 0.044715f * val * val * val);
                    val = val / (1.0f + __expf(-u));
                }
                if (res) val += res[(size_t)mrow * N + n];
                if (outf) outf[(size_t)mrow * N + n] = val;
                if (outb) outb[(size_t)mrow * N + n] = f2b(val);
            }
        }
    }
}

// ---------------- CSR build ----------------
__global__ void hist_kernel(const int* __restrict__ row_index, int* __restrict__ cnt)
{
    int e = blockIdx.x * 256 + threadIdx.x;
    if (e < E_EDGES) atomicAdd(&cnt[row_index[e]], 1);
}

// Parallel exclusive scan over 16384 counts: one block, 1024 threads.
// Each thread owns 16 contiguous counts (int4 x4 coalesced loads), in-thread
// prefix, wave shfl-scan of thread totals, LDS scan of 16 wave sums.
__global__ __launch_bounds__(1024) void scan_kernel(
    const int* __restrict__ cnt, int* __restrict__ row_start,
    int* __restrict__ cursor)
{
    int t = threadIdx.x;
    int4 c0 = ((const int4*)cnt)[t * 4 + 0];
    int4 c1 = ((const int4*)cnt)[t * 4 + 1];
    int4 c2 = ((const int4*)cnt)[t * 4 + 2];
    int4 c3 = ((const int4*)cnt)[t * 4 + 3];
    int v[16] = {c0.x, c0.y, c0.z, c0.w, c1.x, c1.y, c1.z, c1.w,
                 c2.x, c2.y, c2.z, c2.w, c3.x, c3.y, c3.z, c3.w};
    int total = 0;
    int pfx[16];
#pragma unroll
    for (int i = 0; i < 16; i++) { pfx[i] = total; total += v[i]; }
    // wave inclusive scan of totals
    int lane = t & 63, wv = t >> 6;
    int incl = total;
    for (int off = 1; off < 64; off <<= 1) {
        int u = __shfl_up(incl, off);
        if (lane >= off) incl += u;
    }
    __shared__ int wsum[16];
    if (lane == 63) wsum[wv] = incl;
    __syncthreads();
    __shared__ int wbase[16];
    if (t < 16) {
        int s = wsum[t];
        int run = 0;
        // tiny serial scan by thread 0's wave lanes (16 elems): do in lane 0 only
        // -> simpler: each of first 16 threads sums predecessors
        for (int i = 0; i < 16; i++) { if (i < t) run += wsum[i]; }
        wbase[t] = run;
        (void)s;
    }
    __syncthreads();
    int base = wbase[wv] + (incl - total);   // exclusive prefix for this thread
#pragma unroll
    for (int i = 0; i < 4; i++) {
        int4 rs = make_int4(base + pfx[i * 4], base + pfx[i * 4 + 1],
                            base + pfx[i * 4 + 2], base + pfx[i * 4 + 3]);
        ((int4*)row_start)[t * 4 + i] = rs;
        ((int4*)cursor)[t * 4 + i] = rs;
    }
    if (t == 1023) row_start[L_NODES] = base + total;
}

// scatter: emeta[p] = (col, r0, r1, r2); pabp[p*8+h] = pos_att_bias[e*8+h]
__global__ void scatter_kernel(const int* __restrict__ row_index, const int* __restrict__ col_index,
                               const int* __restrict__ to_col_index, const float* __restrict__ dist,
                               const float* __restrict__ pos, const float* __restrict__ col_pos,
                               const float* __restrict__ pos_att_bias,
                               int* __restrict__ cursor, int4* __restrict__ emeta,
                               float* __restrict__ pabp)
{
    int e = blockIdx.x * 256 + threadIdx.x;
    if (e < E_EDGES) {
        int row = row_index[e];
        int p = atomicAdd(&cursor[row], 1);
        int tci = to_col_index[e];
        float dinv = 1.0f / dist[e];
        float r0 = (col_pos[tci * 3]     - pos[row * 3])     * dinv;
        float r1 = (col_pos[tci * 3 + 1] - pos[row * 3 + 1]) * dinv;
        float r2 = (col_pos[tci * 3 + 2] - pos[row * 3 + 2]) * dinv;
        emeta[p] = make_int4(col_index[e], __float_as_int(r0), __float_as_int(r1),
                             __float_as_int(r2));
        const float4* pb = (const float4*)(pos_att_bias + (size_t)e * HEADS);
        float4 b0 = pb[0], b1 = pb[1];
        float4* dst = (float4*)(pabp + (size_t)p * HEADS);
        dst[0] = b0; dst[1] = b1;
    }
}

// ---------------- Edge attention: wave = row (all heads), serial edge loop -----------
__global__ __launch_bounds__(256) void attn_kernel(
    const short* __restrict__ qkv, const int4* __restrict__ emeta,
    const float* __restrict__ pabp, const int* __restrict__ row_start,
    const float* __restrict__ Wvec, const float* __restrict__ bvec,
    short* __restrict__ out_bf)
{
    int lane = threadIdx.x & 63;
    int r = blockIdx.x * 4 + (threadIdx.x >> 6);
    int h = lane >> 3;
    int cbase = lane * 8;                // channels [cbase, cbase+8) of C=512

    float qv[8], wv0[8], wv1[8], wv2[8], bvv[8];
    {
        bf16x8 qh = *(const bf16x8*)(qkv + (size_t)r * QKVDIM + cbase);
#pragma unroll
        for (int j = 0; j < 8; j++) qv[j] = b2f((unsigned short)qh[j]);
        float4 a0 = *(const float4*)(Wvec + cbase);
        float4 a1 = *(const float4*)(Wvec + cbase + 4);
        float4 b0 = *(const float4*)(Wvec + CDIM + cbase);
        float4 b1 = *(const float4*)(Wvec + CDIM + cbase + 4);
        float4 c0 = *(const float4*)(Wvec + 2 * CDIM + cbase);
        float4 c1 = *(const float4*)(Wvec + 2 * CDIM + cbase + 4);
        float4 d0 = *(const float4*)(bvec + cbase);
        float4 d1 = *(const float4*)(bvec + cbase + 4);
        wv0[0]=a0.x; wv0[1]=a0.y; wv0[2]=a0.z; wv0[3]=a0.w; wv0[4]=a1.x; wv0[5]=a1.y; wv0[6]=a1.z; wv0[7]=a1.w;
        wv1[0]=b0.x; wv1[1]=b0.y; wv1[2]=b0.z; wv1[3]=b0.w; wv1[4]=b1.x; wv1[5]=b1.y; wv1[6]=b1.z; wv1[7]=b1.w;
        wv2[0]=c0.x; wv2[1]=c0.y; wv2[2]=c0.z; wv2[3]=c0.w; wv2[4]=c1.x; wv2[5]=c1.y; wv2[6]=c1.z; wv2[7]=c1.w;
        bvv[0]=d0.x; bvv[1]=d0.y; bvv[2]=d0.z; bvv[3]=d0.w; bvv[4]=d1.x; bvv[5]=d1.y; bvv[6]=d1.z; bvv[7]=d1.w;
    }

    int e0 = row_start[r], e1 = row_start[r + 1];
    float m = -1e30f, l = 0.0f;
    float acc[8] = {};

    // 2-deep software pipeline: emeta fetched 2 ahead, k/v + bias fetched 1 ahead.
    int4 em_n, em_n2;
    float pab_n;
    bf16x8 k_n, v_n;
    if (e0 < e1) {
        em_n = emeta[e0];
        em_n2 = emeta[(e0 + 1 < e1) ? e0 + 1 : e1 - 1];
        pab_n = pabp[(size_t)e0 * HEADS + h];
        const short* kp = qkv + (size_t)em_n.x * QKVDIM + CDIM + cbase;
        k_n = *(const bf16x8*)kp;
        v_n = *(const bf16x8*)(kp + CDIM);
    }
    for (int idx = e0; idx < e1; ++idx) {
        int4 em = em_n;
        float pab = pab_n;
        bf16x8 k8 = k_n, v8 = v_n;
        // advance pipeline
        em_n = em_n2;
        int i2 = (idx + 2 < e1) ? idx + 2 : e1 - 1;
        em_n2 = emeta[i2];
        int i1 = (idx + 1 < e1) ? idx + 1 : e1 - 1;
        pab_n = pabp[(size_t)i1 * HEADS + h];
        {
            const short* kp = qkv + (size_t)em_n.x * QKVDIM + CDIM + cbase;
            k_n = *(const bf16x8*)kp;
            v_n = *(const bf16x8*)(kp + CDIM);
        }
        // compute current edge
        float s = 0.0f;
        float vf[8];
#pragma unroll
        for (int j = 0; j < 8; j++) {
            float kf = b2f((unsigned short)k8[j]);
            vf[j] = b2f((unsigned short)v8[j]);
            float d = qv[j] - kf;
            s = fmaf(d, d, s);
        }
        s += __shfl_xor(s, 1);
        s += __shfl_xor(s, 2);
        s += __shfl_xor(s, 4);              // per-head dot (8 lanes of head h)
        float score = -s * 0.125f + pab;
        float mn = fmaxf(m, score);
        float scale = __expf(m - mn);
        float pexp = __expf(score - mn);
        m = mn;
        l = l * scale + pexp;
        float r0 = __int_as_float(em.y), r1 = __int_as_float(em.z), r2 = __int_as_float(em.w);
#pragma unroll
        for (int j = 0; j < 8; j++) {
            float vv = vf[j] + r0 * wv0[j] + r1 * wv1[j] + r2 * wv2[j] + bvv[j];
            acc[j] = fmaf(acc[j], scale, pexp * vv);
        }
    }
    float inv = (l > 0.0f) ? 1.0f / l : 0.0f;
    bf16x8 o;
#pragma unroll
    for (int j = 0; j < 8; j++) o[j] = (short)f2b(acc[j] * inv);
    *(bf16x8*)(out_bf + (size_t)r * CDIM + cbase) = o;
}

// ---------------- launch ----------------
extern "C" void kernel_launch(void* const* d_in, const int* in_sizes, int n_in,
                              void* d_out, int out_size, void* d_ws, size_t ws_size,
                              hipStream_t stream)
{
    const float* x            = (const float*)d_in[0];
    const int*   row_index    = (const int*)d_in[1];
    const int*   col_index    = (const int*)d_in[2];
    const int*   to_col_index = (const int*)d_in[3];
    const float* pos_att_bias = (const float*)d_in[5];
    const float* dist         = (const float*)d_in[6];
    const float* pos          = (const float*)d_in[7];
    const float* col_pos      = (const float*)d_in[8];
    const float* ln1_g = (const float*)d_in[9];
    const float* ln1_b = (const float*)d_in[10];
    const float* ln2_g = (const float*)d_in[11];
    const float* ln2_b = (const float*)d_in[12];
    const float* Wq = (const float*)d_in[13];  const float* bq = (const float*)d_in[14];
    const float* Wk = (const float*)d_in[15];  const float* bk = (const float*)d_in[16];
    const float* Wv = (const float*)d_in[17];  const float* bv = (const float*)d_in[18];
    const float* Wvec = (const float*)d_in[19]; const float* bvec = (const float*)d_in[20];
    const float* Wo = (const float*)d_in[21];  const float* bo = (const float*)d_in[22];
    const float* W1 = (const float*)d_in[23];  const float* b1 = (const float*)d_in[24];
    const float* W2 = (const float*)d_in[25];  const float* b2 = (const float*)d_in[26];

    char* ws = (char*)d_ws;
    size_t off = 0;
    auto alloc = [&](size_t bytes) -> void* {
        void* p = ws + off;
        off = (off + bytes + 255) & ~(size_t)255;
        return p;
    };
    const size_t LC = (size_t)L_NODES * CDIM;
    short* qkvb = (short*)alloc((size_t)L_NODES * QKVDIM * 2);  // q|k|v bf16
    float* x1f  = (float*)alloc(LC * 4);
    short* zbf  = (short*)alloc(LC * 2);            // LN1 out, reused for LN2 out
    short* abf  = (short*)alloc(LC * 2);            // attention out (bf16)
    short* wqkvT = (short*)alloc((size_t)QKVDIM * CDIM * 2);
    short* woT   = (short*)alloc((size_t)CDIM * CDIM * 2);
    short* w1T   = (short*)alloc((size_t)CDIM * HID * 2);
    short* w2T   = (short*)alloc((size_t)HID * CDIM * 2);
    float* bqkv  = (float*)alloc(QKVDIM * 4);
    int* cnt       = (int*)alloc(L_NODES * 4);
    int* cursor    = (int*)alloc(L_NODES * 4);
    int* row_start = (int*)alloc((L_NODES + 1) * 4);
    int4* emeta    = (int4*)alloc((size_t)E_EDGES * 16);
    short* hbf = (short*)qkvb;   // hidden bf16 (L x HID) overlays qkvb (dead after attention)
    float* pabp = x1f;           // permuted bias overlays x1f (x1f written only after attn)

    // prep: all transposes + bias pack + cnt zero (1 launch)
    prep_kernel<<<2118, 256, 0, stream>>>(Wq, Wk, Wv, Wo, W1, W2,
                                          wqkvT, woT, w1T, w2T,
                                          bq, bk, bv, bqkv, cnt);

    // LN1
    ln_bf16_kernel<<<L_NODES, 256, 0, stream>>>(x, ln1_g, ln1_b, zbf);

    // fused QKV GEMM: [16384,1536] bf16, BM=256
    dim3 gqkv(QKVDIM / 128, L_NODES / 256);
    gemm_bf16_kernel<256><<<gqkv, 256, 0, stream>>>(zbf, wqkvT, bqkv, nullptr, nullptr, qkvb,
                                                    L_NODES, QKVDIM, CDIM, 0);

    // CSR build
    hist_kernel<<<E_EDGES / 256, 256, 0, stream>>>(row_index, cnt);
    scan_kernel<<<1, 1024, 0, stream>>>(cnt, row_start, cursor);
    scatter_kernel<<<E_EDGES / 256, 256, 0, stream>>>(row_index, col_index, to_col_index,
                                                      dist, pos, col_pos, pos_att_bias,
                                                      cursor, emeta, pabp);

    // edge attention: wave per row, 4 rows per 256-thread block
    attn_kernel<<<L_NODES / 4, 256, 0, stream>>>(qkvb, emeta, pabp, row_start, Wvec, bvec, abf);

    // Wo GEMM + residual -> x1  (BM=64)
    dim3 gwo(CDIM / 128, L_NODES / 64);
    gemm_bf16_kernel<64><<<gwo, 256, 0, stream>>>(abf, woT, bo, x, x1f, nullptr, L_NODES, CDIM, CDIM, 0);

    // LN2
    ln_bf16_kernel<<<L_NODES, 256, 0, stream>>>(x1f, ln2_g, ln2_b, zbf);

    // FFN
    dim3 g1024(HID / 128, L_NODES / 256);
    gemm_bf16_kernel<256><<<g1024, 256, 0, stream>>>(zbf, w1T, b1, nullptr, nullptr, hbf, L_NODES, HID, CDIM, 1);
    dim3 gw2(CDIM / 128, L_NODES / 64);
    gemm_bf16_kernel<64><<<gw2, 256, 0, stream>>>(hbf, w2T, b2, x1f, (float*)d_out, nullptr, L_NODES, CDIM, HID, 0);
}

// Round 9
// 411.365 us; speedup vs baseline: 1.3809x; 1.1355x over previous
//
#include <hip/hip_runtime.h>

#define L_NODES 16384
#define E_EDGES 131072
#define CDIM 512
#define QKVDIM 1536
#define HEADS 8
#define DHEAD 64
#define HID 1024

typedef __attribute__((ext_vector_type(8))) short bf16x8;
typedef __attribute__((ext_vector_type(4))) float f32x4;

__device__ inline unsigned short f2b(float f) {
    union { float f; unsigned int u; } v{f};
    unsigned int r = (v.u + 0x7fffu + ((v.u >> 16) & 1u)) >> 16;
    return (unsigned short)r;
}
__device__ inline float b2f(unsigned short h) {
    union { unsigned int u; float f; } v;
    v.u = (unsigned int)h << 16;
    return v.f;
}

// async global->LDS, 16B per lane (wave-uniform base + lane*16 semantics)
__device__ inline void async_lds16(const void* g, void* l) {
    __builtin_amdgcn_global_load_lds(
        (const __attribute__((address_space(1))) unsigned int*)g,
        (__attribute__((address_space(3))) unsigned int*)l,
        16, 0, 0);
}

__device__ inline void gelu_res_store(float& val, int act) {
    if (act) {
        float u = 1.5957691216057308f * (val + 0.044715f * val * val * val);
        val = val / (1.0f + __expf(-u));
    }
}

// ---------------- LayerNorm (fp32 in -> bf16 out) ----------------
__global__ __launch_bounds__(256) void ln_bf16_kernel(
    const float* __restrict__ x, const float* __restrict__ g,
    const float* __restrict__ b, short* __restrict__ out)
{
    int row = blockIdx.x;
    int t = threadIdx.x;
    const float2* xr = (const float2*)(x + (size_t)row * CDIM);
    float2 v = xr[t];
    float s = v.x + v.y;
    float sq = v.x * v.x + v.y * v.y;
    for (int off = 32; off; off >>= 1) {
        s += __shfl_xor(s, off);
        sq += __shfl_xor(sq, off);
    }
    __shared__ float ss[4], sqs[4];
    int wave = t >> 6, lane = t & 63;
    if (lane == 0) { ss[wave] = s; sqs[wave] = sq; }
    __syncthreads();
    s = ss[0] + ss[1] + ss[2] + ss[3];
    sq = sqs[0] + sqs[1] + sqs[2] + sqs[3];
    float mu = s * (1.0f / CDIM);
    float var = sq * (1.0f / CDIM) - mu * mu;
    float inv = rsqrtf(var + 1e-5f);
    int c = t * 2;
    unsigned short h0 = f2b((v.x - mu) * inv * g[c] + b[c]);
    unsigned short h1 = f2b((v.y - mu) * inv * g[c + 1] + b[c + 1]);
    unsigned int packed = ((unsigned int)h1 << 16) | h0;
    *(unsigned int*)(out + (size_t)row * CDIM + c) = packed;
}

// ---------------- Prep: all weight transposes + bias pack + cnt zero, one launch ----
__global__ __launch_bounds__(256) void prep_kernel(
    const float* __restrict__ Wq, const float* __restrict__ Wk,
    const float* __restrict__ Wv, const float* __restrict__ Wo,
    const float* __restrict__ W1, const float* __restrict__ W2,
    short* __restrict__ wqkvT, short* __restrict__ woT,
    short* __restrict__ w1T, short* __restrict__ w2T,
    const float* __restrict__ bq, const float* __restrict__ bk,
    const float* __restrict__ bv, float* __restrict__ bqkv,
    int* __restrict__ cnt)
{
    int bid = blockIdx.x;
    if (bid >= 2054) {                       // zero cnt
        cnt[(bid - 2054) * 256 + threadIdx.x] = 0;
        return;
    }
    if (bid >= 2048) {                       // bias pack (1536 elems over 6 blocks)
        int i = (bid - 2048) * 256 + threadIdx.x;
        float val = (i < CDIM) ? bq[i] : (i < 2 * CDIM) ? bk[i - CDIM] : bv[i - 2 * CDIM];
        bqkv[i] = val;
        return;
    }
    const float* W; short* WT; int K, N, tn, tk;
    if (bid < 1024) {
        int w = bid >> 8, local = bid & 255;
        tn = local & 15; tk = local >> 4; K = 512; N = 512;
        W = (w == 0) ? Wq : (w == 1) ? Wk : (w == 2) ? Wv : Wo;
        WT = (w == 3) ? woT : wqkvT + (size_t)w * 512 * 512;
    } else if (bid < 1536) {
        int local = bid - 1024;
        tn = local & 31; tk = local >> 5; K = 512; N = 1024;
        W = W1; WT = w1T;
    } else {
        int local = bid - 1536;
        tn = local & 15; tk = local >> 4; K = 1024; N = 512;
        W = W2; WT = w2T;
    }
    __shared__ float tile[32][33];
    int tx = threadIdx.x & 31, ty = threadIdx.x >> 5;
    int n0 = tn * 32, k0 = tk * 32;
#pragma unroll
    for (int r = 0; r < 4; r++)
        tile[ty + r * 8][tx] = W[(size_t)(k0 + ty + r * 8) * N + n0 + tx];
    __syncthreads();
#pragma unroll
    for (int r = 0; r < 4; r++)
        WT[(size_t)(n0 + ty + r * 8) * K + k0 + tx] = f2b(tile[tx][ty + r * 8]);
}

// ---------------- Wave-private barrier-free bf16 MFMA GEMM ----------------
// C[M][N] = A[M][K] @ B^T[N][K]. Block 128x128 = 4 independent waves, each
// computing a private 64x64 tile with its OWN 2-stage LDS pipeline (8KB/stage).
// NO s_barrier anywhere -> the compiler cannot force a vmcnt(0) drain; the
// per-wave s_waitcnt vmcnt(8) waits only the stage being consumed while the
// next stage's 8 loads stay in flight. lgkmcnt(0) before reissuing a buffer
// guarantees prior ds_reads of it completed.
__global__ __launch_bounds__(256) void gemm_wp_kernel(
    const short* __restrict__ A, const short* __restrict__ B,
    const float* __restrict__ bias, const float* __restrict__ res,
    float* __restrict__ outf, short* __restrict__ outb,
    int M, int N, int K, int act)
{
    __shared__ short lds[4 * 2 * 4096];      // [wave][stage][A 2048 | B 2048] shorts, 64KB
    int t = threadIdx.x;
    int wave = t >> 6, lane = t & 63;
    int bm = blockIdx.y * 128 + (wave & 1) * 64;
    int bn = blockIdx.x * 128 + (wave >> 1) * 64;
    int crow = lane & 15, quad = lane >> 4;
    short* wbase = lds + wave * 8192;

    f32x4 acc[4][4] = {};
    const int niter = K >> 5;

    auto stage = [&](int s, int k0) {
        short* dstA = wbase + s * 4096;
        short* dstB = dstA + 2048;
        int row = (lane >> 2), chunk = lane & 3;
#pragma unroll
        for (int a = 0; a < 4; a++)
            async_lds16(A + (size_t)(bm + a * 16 + row) * K + k0 + chunk * 8,
                        (char*)dstA + a * 1024 + lane * 16);
#pragma unroll
        for (int a = 0; a < 4; a++)
            async_lds16(B + (size_t)(bn + a * 16 + row) * K + k0 + chunk * 8,
                        (char*)dstB + a * 1024 + lane * 16);
    };

    stage(0, 0);
    stage(1, 32);                            // K >= 64 always

    for (int i = 0; i < niter; ++i) {
        const short* Ab = wbase + (i & 1) * 4096;
        const short* Bb = Ab + 2048;
        if (i + 1 < niter) asm volatile("s_waitcnt vmcnt(8)" ::: "memory");
        else               asm volatile("s_waitcnt vmcnt(0)" ::: "memory");
        bf16x8 af[4], bg[4];
#pragma unroll
        for (int ii = 0; ii < 4; ii++)
            af[ii] = *(const bf16x8*)&Ab[(ii * 16 + crow) * 32 + quad * 8];
#pragma unroll
        for (int j = 0; j < 4; j++)
            bg[j] = *(const bf16x8*)&Bb[(j * 16 + crow) * 32 + quad * 8];
        asm volatile("s_waitcnt lgkmcnt(0)" ::: "memory");   // reads done before overwrite
        if (i + 2 < niter) stage(i & 1, (i + 2) << 5);
#pragma unroll
        for (int ii = 0; ii < 4; ii++)
#pragma unroll
            for (int j = 0; j < 4; j++)
                acc[ii][j] = __builtin_amdgcn_mfma_f32_16x16x32_bf16(af[ii], bg[j], acc[ii][j], 0, 0, 0);
    }

#pragma unroll
    for (int i = 0; i < 4; i++) {
#pragma unroll
        for (int j = 0; j < 4; j++) {
            int n = bn + j * 16 + crow;
            float bi = bias ? bias[n] : 0.0f;
#pragma unroll
            for (int r = 0; r < 4; r++) {
                int mrow = bm + i * 16 + quad * 4 + r;
                float val = acc[i][j][r] + bi;
                gelu_res_store(val, act);
                if (res) val += res[(size_t)mrow * N + n];
                if (outf) outf[(size_t)mrow * N + n] = val;
                if (outb) outb[(size_t)mrow * N + n] = f2b(val);
            }
        }
    }
}

// ---------------- bf16 MFMA GEMM, 3-stage pipelined LDS K-loop (BM=64) --------------
__global__ __launch_bounds__(256) void gemm_bf16_kernel(
    const short* __restrict__ A, const short* __restrict__ B,
    const float* __restrict__ bias, const float* __restrict__ res,
    float* __restrict__ outf, short* __restrict__ outb,
    int M, int N, int K, int act)
{
    constexpr int BM = 64;
    constexpr int MI = 2;
    __shared__ short As[3 * BM * 32];
    __shared__ short Bs[3 * 128 * 32];
    int t = threadIdx.x;
    int bm = blockIdx.y * BM, bn = blockIdx.x * 128;
    int wave = t >> 6, lane = t & 63;
    int wm = (wave & 1) * 32, wn = (wave >> 1) * 64;
    int crow = lane & 15, quad = lane >> 4;

    f32x4 acc[MI][4] = {};

    const int niter = K >> 5;
    auto stage = [&](int s, int k0) {
        {
            int idx = t;
            int row = idx >> 2, chunk = idx & 3;
            async_lds16(A + (size_t)(bm + row) * K + k0 + chunk * 8,
                        (char*)As + s * 4096 + idx * 16);
        }
#pragma unroll
        for (int c = 0; c < 2; c++) {
            int idx = c * 256 + t;
            int row = idx >> 2, chunk = idx & 3;
            async_lds16(B + (size_t)(bn + row) * K + k0 + chunk * 8,
                        (char*)Bs + s * 8192 + idx * 16);
        }
    };

    stage(0, 0);
    stage(1, 32);

    for (int i = 0; i < niter; ++i) {
        int cur = i % 3;
        if (i + 1 < niter) asm volatile("s_waitcnt vmcnt(3)" ::: "memory");
        else               asm volatile("s_waitcnt vmcnt(0)" ::: "memory");
        __builtin_amdgcn_s_barrier();
        if (i + 2 < niter) stage((i + 2) % 3, (i + 2) << 5);

        const short* Ab = As + cur * (BM * 32);
        const short* Bb = Bs + cur * (128 * 32);
        bf16x8 af[MI], bg[4];
#pragma unroll
        for (int ii = 0; ii < MI; ii++)
            af[ii] = *(const bf16x8*)&Ab[(wm + ii * 16 + crow) * 32 + quad * 8];
#pragma unroll
        for (int j = 0; j < 4; j++)
            bg[j] = *(const bf16x8*)&Bb[(wn + j * 16 + crow) * 32 + quad * 8];
#pragma unroll
        for (int ii = 0; ii < MI; ii++)
#pragma unroll
            for (int j = 0; j < 4; j++)
                acc[ii][j] = __builtin_amdgcn_mfma_f32_16x16x32_bf16(af[ii], bg[j], acc[ii][j], 0, 0, 0);
    }

#pragma unroll
    for (int i = 0; i < MI; i++) {
#pragma unroll
        for (int j = 0; j < 4; j++) {
            int n = bn + wn + j * 16 + crow;
            float bi = bias ? bias[n] : 0.0f;
#pragma unroll
            for (int r = 0; r < 4; r++) {
                int mrow = bm + wm + i * 16 + quad * 4 + r;
                float val = acc[i][j][r] + bi;
                gelu_res_store(val, act);
                if (res) val += res[(size_t)mrow * N + n];
                if (outf) outf[(size_t)mrow * N + n] = val;
                if (outb) outb[(size_t)mrow * N + n] = f2b(val);
            }
        }
    }
}

// ---------------- CSR build ----------------
__global__ void hist_kernel(const int* __restrict__ row_index, int* __restrict__ cnt)
{
    int e = blockIdx.x * 256 + threadIdx.x;
    if (e < E_EDGES) atomicAdd(&cnt[row_index[e]], 1);
}

// Parallel exclusive scan over 16384 counts: one block, 1024 threads.
__global__ __launch_bounds__(1024) void scan_kernel(
    const int* __restrict__ cnt, int* __restrict__ row_start,
    int* __restrict__ cursor)
{
    int t = threadIdx.x;
    int4 c0 = ((const int4*)cnt)[t * 4 + 0];
    int4 c1 = ((const int4*)cnt)[t * 4 + 1];
    int4 c2 = ((const int4*)cnt)[t * 4 + 2];
    int4 c3 = ((const int4*)cnt)[t * 4 + 3];
    int v[16] = {c0.x, c0.y, c0.z, c0.w, c1.x, c1.y, c1.z, c1.w,
                 c2.x, c2.y, c2.z, c2.w, c3.x, c3.y, c3.z, c3.w};
    int total = 0;
    int pfx[16];
#pragma unroll
    for (int i = 0; i < 16; i++) { pfx[i] = total; total += v[i]; }
    int lane = t & 63, wv = t >> 6;
    int incl = total;
    for (int off = 1; off < 64; off <<= 1) {
        int u = __shfl_up(incl, off);
        if (lane >= off) incl += u;
    }
    __shared__ int wsum[16];
    if (lane == 63) wsum[wv] = incl;
    __syncthreads();
    __shared__ int wbase[16];
    if (t < 16) {
        int run = 0;
        for (int i = 0; i < 16; i++) { if (i < t) run += wsum[i]; }
        wbase[t] = run;
    }
    __syncthreads();
    int base = wbase[wv] + (incl - total);   // exclusive prefix for this thread
#pragma unroll
    for (int i = 0; i < 4; i++) {
        int4 rs = make_int4(base + pfx[i * 4], base + pfx[i * 4 + 1],
                            base + pfx[i * 4 + 2], base + pfx[i * 4 + 3]);
        ((int4*)row_start)[t * 4 + i] = rs;
        ((int4*)cursor)[t * 4 + i] = rs;
    }
    if (t == 1023) row_start[L_NODES] = base + total;
}

// scatter: emeta[p] = (col, r0, r1, r2); pabp[p*8+h] = pos_att_bias[e*8+h]
__global__ void scatter_kernel(const int* __restrict__ row_index, const int* __restrict__ col_index,
                               const int* __restrict__ to_col_index, const float* __restrict__ dist,
                               const float* __restrict__ pos, const float* __restrict__ col_pos,
                               const float* __restrict__ pos_att_bias,
                               int* __restrict__ cursor, int4* __restrict__ emeta,
                               float* __restrict__ pabp)
{
    int e = blockIdx.x * 256 + threadIdx.x;
    if (e < E_EDGES) {
        int row = row_index[e];
        int p = atomicAdd(&cursor[row], 1);
        int tci = to_col_index[e];
        float dinv = 1.0f / dist[e];
        float r0 = (col_pos[tci * 3]     - pos[row * 3])     * dinv;
        float r1 = (col_pos[tci * 3 + 1] - pos[row * 3 + 1]) * dinv;
        float r2 = (col_pos[tci * 3 + 2] - pos[row * 3 + 2]) * dinv;
        emeta[p] = make_int4(col_index[e], __float_as_int(r0), __float_as_int(r1),
                             __float_as_int(r2));
        const float4* pb = (const float4*)(pos_att_bias + (size_t)e * HEADS);
        float4 b0 = pb[0], b1 = pb[1];
        float4* dst = (float4*)(pabp + (size_t)p * HEADS);
        dst[0] = b0; dst[1] = b1;
    }
}

// ---------------- Edge attention: wave = row (all heads), serial edge loop -----------
__global__ __launch_bounds__(256) void attn_kernel(
    const short* __restrict__ qkv, const int4* __restrict__ emeta,
    const float* __restrict__ pabp, const int* __restrict__ row_start,
    const float* __restrict__ Wvec, const float* __restrict__ bvec,
    short* __restrict__ out_bf)
{
    int lane = threadIdx.x & 63;
    int r = blockIdx.x * 4 + (threadIdx.x >> 6);
    int h = lane >> 3;
    int cbase = lane * 8;                // channels [cbase, cbase+8) of C=512

    float qv[8], wv0[8], wv1[8], wv2[8], bvv[8];
    {
        bf16x8 qh = *(const bf16x8*)(qkv + (size_t)r * QKVDIM + cbase);
#pragma unroll
        for (int j = 0; j < 8; j++) qv[j] = b2f((unsigned short)qh[j]);
        float4 a0 = *(const float4*)(Wvec + cbase);
        float4 a1 = *(const float4*)(Wvec + cbase + 4);
        float4 b0 = *(const float4*)(Wvec + CDIM + cbase);
        float4 b1 = *(const float4*)(Wvec + CDIM + cbase + 4);
        float4 c0 = *(const float4*)(Wvec + 2 * CDIM + cbase);
        float4 c1 = *(const float4*)(Wvec + 2 * CDIM + cbase + 4);
        float4 d0 = *(const float4*)(bvec + cbase);
        float4 d1 = *(const float4*)(bvec + cbase + 4);
        wv0[0]=a0.x; wv0[1]=a0.y; wv0[2]=a0.z; wv0[3]=a0.w; wv0[4]=a1.x; wv0[5]=a1.y; wv0[6]=a1.z; wv0[7]=a1.w;
        wv1[0]=b0.x; wv1[1]=b0.y; wv1[2]=b0.z; wv1[3]=b0.w; wv1[4]=b1.x; wv1[5]=b1.y; wv1[6]=b1.z; wv1[7]=b1.w;
        wv2[0]=c0.x; wv2[1]=c0.y; wv2[2]=c0.z; wv2[3]=c0.w; wv2[4]=c1.x; wv2[5]=c1.y; wv2[6]=c1.z; wv2[7]=c1.w;
        bvv[0]=d0.x; bvv[1]=d0.y; bvv[2]=d0.z; bvv[3]=d0.w; bvv[4]=d1.x; bvv[5]=d1.y; bvv[6]=d1.z; bvv[7]=d1.w;
    }

    int e0 = row_start[r], e1 = row_start[r + 1];
    float m = -1e30f, l = 0.0f;
    float acc[8] = {};

    int4 em_n, em_n2;
    float pab_n;
    bf16x8 k_n, v_n;
    if (e0 < e1) {
        em_n = emeta[e0];
        em_n2 = emeta[(e0 + 1 < e1) ? e0 + 1 : e1 - 1];
        pab_n = pabp[(size_t)e0 * HEADS + h];
        const short* kp = qkv + (size_t)em_n.x * QKVDIM + CDIM + cbase;
        k_n = *(const bf16x8*)kp;
        v_n = *(const bf16x8*)(kp + CDIM);
    }
    for (int idx = e0; idx < e1; ++idx) {
        int4 em = em_n;
        float pab = pab_n;
        bf16x8 k8 = k_n, v8 = v_n;
        em_n = em_n2;
        int i2 = (idx + 2 < e1) ? idx + 2 : e1 - 1;
        em_n2 = emeta[i2];
        int i1 = (idx + 1 < e1) ? idx + 1 : e1 - 1;
        pab_n = pabp[(size_t)i1 * HEADS + h];
        {
            const short* kp = qkv + (size_t)em_n.x * QKVDIM + CDIM + cbase;
            k_n = *(const bf16x8*)kp;
            v_n = *(const bf16x8*)(kp + CDIM);
        }
        float s = 0.0f;
        float vf[8];
#pragma unroll
        for (int j = 0; j < 8; j++) {
            float kf = b2f((unsigned short)k8[j]);
            vf[j] = b2f((unsigned short)v8[j]);
            float d = qv[j] - kf;
            s = fmaf(d, d, s);
        }
        s += __shfl_xor(s, 1);
        s += __shfl_xor(s, 2);
        s += __shfl_xor(s, 4);
        float score = -s * 0.125f + pab;
        float mn = fmaxf(m, score);
        float scale = __expf(m - mn);
        float pexp = __expf(score - mn);
        m = mn;
        l = l * scale + pexp;
        float r0 = __int_as_float(em.y), r1 = __int_as_float(em.z), r2 = __int_as_float(em.w);
#pragma unroll
        for (int j = 0; j < 8; j++) {
            float vv = vf[j] + r0 * wv0[j] + r1 * wv1[j] + r2 * wv2[j] + bvv[j];
            acc[j] = fmaf(acc[j], scale, pexp * vv);
        }
    }
    float inv = (l > 0.0f) ? 1.0f / l : 0.0f;
    bf16x8 o;
#pragma unroll
    for (int j = 0; j < 8; j++) o[j] = (short)f2b(acc[j] * inv);
    *(bf16x8*)(out_bf + (size_t)r * CDIM + cbase) = o;
}

// ---------------- launch ----------------
extern "C" void kernel_launch(void* const* d_in, const int* in_sizes, int n_in,
                              void* d_out, int out_size, void* d_ws, size_t ws_size,
                              hipStream_t stream)
{
    const float* x            = (const float*)d_in[0];
    const int*   row_index    = (const int*)d_in[1];
    const int*   col_index    = (const int*)d_in[2];
    const int*   to_col_index = (const int*)d_in[3];
    const float* pos_att_bias = (const float*)d_in[5];
    const float* dist         = (const float*)d_in[6];
    const float* pos          = (const float*)d_in[7];
    const float* col_pos      = (const float*)d_in[8];
    const float* ln1_g = (const float*)d_in[9];
    const float* ln1_b = (const float*)d_in[10];
    const float* ln2_g = (const float*)d_in[11];
    const float* ln2_b = (const float*)d_in[12];
    const float* Wq = (const float*)d_in[13];  const float* bq = (const float*)d_in[14];
    const float* Wk = (const float*)d_in[15];  const float* bk = (const float*)d_in[16];
    const float* Wv = (const float*)d_in[17];  const float* bv = (const float*)d_in[18];
    const float* Wvec = (const float*)d_in[19]; const float* bvec = (const float*)d_in[20];
    const float* Wo = (const float*)d_in[21];  const float* bo = (const float*)d_in[22];
    const float* W1 = (const float*)d_in[23];  const float* b1 = (const float*)d_in[24];
    const float* W2 = (const float*)d_in[25];  const float* b2 = (const float*)d_in[26];

    char* ws = (char*)d_ws;
    size_t off = 0;
    auto alloc = [&](size_t bytes) -> void* {
        void* p = ws + off;
        off = (off + bytes + 255) & ~(size_t)255;
        return p;
    };
    const size_t LC = (size_t)L_NODES * CDIM;
    short* qkvb = (short*)alloc((size_t)L_NODES * QKVDIM * 2);  // q|k|v bf16
    float* x1f  = (float*)alloc(LC * 4);
    short* zbf  = (short*)alloc(LC * 2);            // LN1 out, reused for LN2 out
    short* abf  = (short*)alloc(LC * 2);            // attention out (bf16)
    short* wqkvT = (short*)alloc((size_t)QKVDIM * CDIM * 2);
    short* woT   = (short*)alloc((size_t)CDIM * CDIM * 2);
    short* w1T   = (short*)alloc((size_t)CDIM * HID * 2);
    short* w2T   = (short*)alloc((size_t)HID * CDIM * 2);
    float* bqkv  = (float*)alloc(QKVDIM * 4);
    int* cnt       = (int*)alloc(L_NODES * 4);
    int* cursor    = (int*)alloc(L_NODES * 4);
    int* row_start = (int*)alloc((L_NODES + 1) * 4);
    int4* emeta    = (int4*)alloc((size_t)E_EDGES * 16);
    short* hbf = (short*)qkvb;   // hidden bf16 (L x HID) overlays qkvb (dead after attention)
    float* pabp = x1f;           // permuted bias overlays x1f (x1f written only after attn)

    // prep: all transposes + bias pack + cnt zero (1 launch)
    prep_kernel<<<2118, 256, 0, stream>>>(Wq, Wk, Wv, Wo, W1, W2,
                                          wqkvT, woT, w1T, w2T,
                                          bq, bk, bv, bqkv, cnt);

    // LN1
    ln_bf16_kernel<<<L_NODES, 256, 0, stream>>>(x, ln1_g, ln1_b, zbf);

    // fused QKV GEMM: [16384,1536] bf16 — wave-private barrier-free
    dim3 gqkv(QKVDIM / 128, L_NODES / 128);
    gemm_wp_kernel<<<gqkv, 256, 0, stream>>>(zbf, wqkvT, bqkv, nullptr, nullptr, qkvb,
                                             L_NODES, QKVDIM, CDIM, 0);

    // CSR build
    hist_kernel<<<E_EDGES / 256, 256, 0, stream>>>(row_index, cnt);
    scan_kernel<<<1, 1024, 0, stream>>>(cnt, row_start, cursor);
    scatter_kernel<<<E_EDGES / 256, 256, 0, stream>>>(row_index, col_index, to_col_index,
                                                      dist, pos, col_pos, pos_att_bias,
                                                      cursor, emeta, pabp);

    // edge attention: wave per row, 4 rows per 256-thread block
    attn_kernel<<<L_NODES / 4, 256, 0, stream>>>(qkvb, emeta, pabp, row_start, Wvec, bvec, abf);

    // Wo GEMM + residual -> x1  (BM=64, 3-stage barrier structure)
    dim3 gwo(CDIM / 128, L_NODES / 64);
    gemm_bf16_kernel<<<gwo, 256, 0, stream>>>(abf, woT, bo, x, x1f, nullptr, L_NODES, CDIM, CDIM, 0);

    // LN2
    ln_bf16_kernel<<<L_NODES, 256, 0, stream>>>(x1f, ln2_g, ln2_b, zbf);

    // FFN: W1 wave-private barrier-free, W2 BM=64 3-stage
    dim3 g1024(HID / 128, L_NODES / 128);
    gemm_wp_kernel<<<g1024, 256, 0, stream>>>(zbf, w1T, b1, nullptr, nullptr, hbf, L_NODES, HID, CDIM, 1);
    dim3 gw2(CDIM / 128, L_NODES / 64);
    gemm_bf16_kernel<<<gw2, 256, 0, stream>>>(hbf, w2T, b2, x1f, (float*)d_out, nullptr, L_NODES, CDIM, HID, 0);
}